// Round 1
// baseline (2472.590 us; speedup 1.0000x reference)
//
#include <hip/hip_runtime.h>
#include <math.h>

// ---------------------------------------------------------------------------
// SeasonalFNO1D: B=64, T=8192, F=6, MODES=32, WIDTH=64, LAYERS=4, FC1=128, OUT=7
// Output = only last time step -> [B, 7, 1].
//
// Structure:
//   x = fc0(inputs)                       [B,T,64]   (full)
//   for l in 0..3:
//     X[b,k,c]  = sum_t x[b,t,c] e^{-2pi i k t/T}   (k<32)  -- pruned DFT
//     Y[b,k,o]  = sum_c X[b,k,c] (wr+i wi)[l,k,c,o]
//     xf[b,t,o] = (1/T)(Re Y0 + 2 sum_{k=1..31} Re(Yk e^{+2pi i k t/T}))
//     x = gelu(xf + x@conv_w[l] + conv_b[l])        (full for l<3; t=T-1 only for l=3)
//   out = fc2(gelu(fc1(x[:,T-1])))
// ---------------------------------------------------------------------------

constexpr int B = 64, T = 8192, F = 6, MODES = 32, C = 64, FC1N = 128, OUTN = 7;
constexpr int TMASK = T - 1;
constexpr int TS = 1024, NCH = T / TS;   // DFT t-chunking (deterministic partials)
constexpr int ROWS = 64;                 // rows per combine block

__device__ __forceinline__ float gelu_exact(float v) {
    return 0.5f * v * (1.0f + erff(v * 0.70710678118654752f));
}

// tw[n] = (cos, sin)(2*pi*n/T)
__global__ void twid_k(float2* __restrict__ tw) {
    int n = blockIdx.x * 256 + threadIdx.x;
    double th = 6.283185307179586476925286766559 * (double)n / (double)T;
    tw[n] = make_float2((float)cos(th), (float)sin(th));
}

// x[row, c] = sum_f in[row, f] * w[f, c] + b[c]
__global__ void fc0_k(const float* __restrict__ in, const float* __restrict__ w,
                      const float* __restrict__ bias, float* __restrict__ x) {
    int tid = threadIdx.x;
    size_t row = (size_t)blockIdx.x * 4 + (tid >> 6);
    int c = tid & 63;
    const float* ip = in + row * F;
    float acc = bias[c];
#pragma unroll
    for (int f = 0; f < F; f++) acc = fmaf(ip[f], w[f * C + c], acc);
    x[row * C + c] = acc;
}

// Partial pruned DFT over one t-chunk. Block = (chunk ch, batch b), 256 thr.
// thread: c = tid&63, k-quad kq = tid>>6 handles k = kq*8 + j, j<8.
// part[((b*NCH+ch)*MODES + k)*C + c] = (sum_t x*cos, -sum_t x*sin)
__global__ void __launch_bounds__(256) dft_partial(const float* __restrict__ x,
                                                   const float2* __restrict__ tw,
                                                   float2* __restrict__ part) {
    __shared__ float2 ltw[T];  // 64 KiB twiddle table
    int b = blockIdx.y, ch = blockIdx.x, tid = threadIdx.x;
    for (int i = tid; i < T; i += 256) ltw[i] = tw[i];
    __syncthreads();
    int c = tid & 63, kq = tid >> 6;
    float accr[8], acci[8];
    int n[8];
    int t0 = ch * TS;
#pragma unroll
    for (int j = 0; j < 8; j++) {
        accr[j] = 0.f; acci[j] = 0.f;
        n[j] = ((kq * 8 + j) * t0) & TMASK;
    }
    const float* xp = x + ((size_t)b * T + t0) * C + c;
    for (int t = 0; t < TS; t++) {
        float xv = xp[(size_t)t * C];
#pragma unroll
        for (int j = 0; j < 8; j++) {
            float2 w = ltw[n[j]];
            accr[j] = fmaf(xv, w.x, accr[j]);
            acci[j] = fmaf(xv, -w.y, acci[j]);
            n[j] = (n[j] + kq * 8 + j) & TMASK;   // n = k*t mod T, incremental
        }
    }
#pragma unroll
    for (int j = 0; j < 8; j++) {
        int k = kq * 8 + j;
        part[(((size_t)b * NCH + ch) * MODES + k) * C + c] = make_float2(accr[j], acci[j]);
    }
}

// Reduce partials + complex mode mix: Y[b,k,o] = sum_c X[b,k,c]*(wr+i wi)[k,c,o]
// grid (MODES, B), 64 threads (thread = o).
__global__ void mode_mix(const float2* __restrict__ part, const float* __restrict__ wr,
                         const float* __restrict__ wi, float2* __restrict__ Y) {
    int b = blockIdx.y, k = blockIdx.x, o = threadIdx.x;
    __shared__ float xr[C], xi[C];
    float sr = 0.f, si = 0.f;
    for (int ch = 0; ch < NCH; ch++) {
        float2 p = part[(((size_t)b * NCH + ch) * MODES + k) * C + o];
        sr += p.x; si += p.y;
    }
    xr[o] = sr; xi[o] = si;
    __syncthreads();
    float ar = 0.f, ai = 0.f;
    for (int c = 0; c < C; c++) {
        float wrr = wr[((size_t)k * C + c) * C + o];
        float wii = wi[((size_t)k * C + c) * C + o];
        float Xr = xr[c], Xi = xi[c];
        ar = fmaf(Xr, wrr, ar); ar = fmaf(-Xi, wii, ar);
        ai = fmaf(Xr, wii, ai); ai = fmaf(Xi, wrr, ai);
    }
    Y[((size_t)b * MODES + k) * C + o] = make_float2(ar, ai);
}

// Fused irfft (32 modes) + conv (64x64) + bias + exact GELU, in-place on x.
// grid (T/ROWS, B), 256 threads; each wave handles one row at a time (4 rows/iter).
__global__ void __launch_bounds__(256) combine_k(float* __restrict__ x, const float2* __restrict__ Y,
                                                 const float2* __restrict__ tw,
                                                 const float* __restrict__ cw,
                                                 const float* __restrict__ cb) {
    __shared__ float yr[MODES][C], yi[MODES][C];  // 16 KiB
    __shared__ float lw[C][C];                    // 16 KiB
    __shared__ float lx[4][C];
    __shared__ float lb[C];
    int b = blockIdx.y, tid = threadIdx.x;
    int t0 = blockIdx.x * ROWS;
    int o = tid & 63, wv = tid >> 6;
    for (int i = tid; i < MODES * C; i += 256) {
        float2 y = Y[(size_t)b * (MODES * C) + i];
        yr[i >> 6][i & 63] = y.x; yi[i >> 6][i & 63] = y.y;
    }
    for (int i = tid; i < C * C; i += 256) lw[i >> 6][i & 63] = cw[i];
    if (tid < C) lb[tid] = cb[tid];
    __syncthreads();
    for (int r0 = 0; r0 < ROWS; r0 += 4) {
        int t = t0 + r0 + wv;
        size_t base = ((size_t)b * T + t) * (size_t)C;
        lx[wv][o] = x[base + o];
        __syncthreads();
        // irfft at time t, channel o (imag of bin 0 ignored, numpy c2r semantics)
        float a2 = 0.f;
        for (int k = 1; k < MODES; k++) {
            float2 w = tw[(k * t) & TMASK];
            a2 = fmaf(yr[k][o], w.x, a2);
            a2 = fmaf(-yi[k][o], w.y, a2);
        }
        float xf = (yr[0][o] + 2.f * a2) * (1.0f / (float)T);
        // conv: row @ conv_w
        float cv = lb[o];
        for (int cc = 0; cc < C; cc++) cv = fmaf(lx[wv][cc], lw[cc][o], cv);
        float g = gelu_exact(xf + cv);
        __syncthreads();
        x[base + o] = g;
    }
}

// Layer 3 at t=T-1 only, then fc1+gelu, fc2. grid B, 128 threads.
__global__ void final_k(const float* __restrict__ x3, const float2* __restrict__ Y3,
                        const float2* __restrict__ tw, const float* __restrict__ cw,
                        const float* __restrict__ cb, const float* __restrict__ w1,
                        const float* __restrict__ b1, const float* __restrict__ w2,
                        const float* __restrict__ b2, float* __restrict__ out) {
    int b = blockIdx.x, tid = threadIdx.x;
    __shared__ float xrow[C];   // x3[b, T-1, :]
    __shared__ float xl[C];     // layer-3 output row
    __shared__ float h[FC1N];
    if (tid < C) xrow[tid] = x3[((size_t)b * T + (T - 1)) * C + tid];
    __syncthreads();
    if (tid < C) {
        int o = tid;
        const float2* Yb = Y3 + (size_t)b * (MODES * C);
        float a2 = 0.f;
        for (int k = 1; k < MODES; k++) {
            float2 w = tw[(k * (T - 1)) & TMASK];
            float2 y = Yb[k * C + o];
            a2 = fmaf(y.x, w.x, a2);
            a2 = fmaf(-y.y, w.y, a2);
        }
        float xf = (Yb[o].x + 2.f * a2) * (1.0f / (float)T);
        float cv = cb[o];
        for (int c = 0; c < C; c++) cv = fmaf(xrow[c], cw[c * C + o], cv);
        xl[o] = gelu_exact(xf + cv);
    }
    __syncthreads();
    {
        int j = tid;
        float acc = b1[j];
        for (int c = 0; c < C; c++) acc = fmaf(xl[c], w1[c * FC1N + j], acc);
        h[j] = gelu_exact(acc);
    }
    __syncthreads();
    if (tid < OUTN) {
        float acc = b2[tid];
        for (int j = 0; j < FC1N; j++) acc = fmaf(h[j], w2[j * OUTN + tid], acc);
        out[b * OUTN + tid] = acc;
    }
}

extern "C" void kernel_launch(void* const* d_in, const int* in_sizes, int n_in,
                              void* d_out, int out_size, void* d_ws, size_t ws_size,
                              hipStream_t stream) {
    const float* inp   = (const float*)d_in[0];
    const float* fc0_w = (const float*)d_in[1];
    const float* fc0_b = (const float*)d_in[2];
    const float* fwr   = (const float*)d_in[3];
    const float* fwi   = (const float*)d_in[4];
    const float* cw    = (const float*)d_in[5];
    const float* cb    = (const float*)d_in[6];
    const float* w1    = (const float*)d_in[7];
    const float* b1    = (const float*)d_in[8];
    const float* w2    = (const float*)d_in[9];
    const float* b2    = (const float*)d_in[10];
    float* out = (float*)d_out;

    // Workspace layout
    char* ws = (char*)d_ws;
    float*  x    = (float*)ws;                                   // 134,217,728 B
    size_t  off  = (size_t)B * T * C * sizeof(float);
    float2* part = (float2*)(ws + off);                          // 8,388,608 B
    off += (size_t)B * NCH * MODES * C * sizeof(float2);
    float2* Y    = (float2*)(ws + off);                          // 1,048,576 B
    off += (size_t)B * MODES * C * sizeof(float2);
    float2* tw   = (float2*)(ws + off);                          // 65,536 B

    twid_k<<<T / 256, 256, 0, stream>>>(tw);
    fc0_k<<<B * T / 4, 256, 0, stream>>>(inp, fc0_w, fc0_b, x);

    for (int l = 0; l < 4; l++) {
        dft_partial<<<dim3(NCH, B), 256, 0, stream>>>(x, tw, part);
        mode_mix<<<dim3(MODES, B), 64, 0, stream>>>(part, fwr + (size_t)l * MODES * C * C,
                                                    fwi + (size_t)l * MODES * C * C, Y);
        if (l < 3) {
            combine_k<<<dim3(T / ROWS, B), 256, 0, stream>>>(x, Y, tw, cw + (size_t)l * C * C,
                                                             cb + (size_t)l * C);
        }
    }
    final_k<<<B, FC1N, 0, stream>>>(x, Y, tw, cw + (size_t)3 * C * C, cb + (size_t)3 * C,
                                    w1, b1, w2, b2, out);
}

// Round 2
// 1334.883 us; speedup vs baseline: 1.8523x; 1.8523x over previous
//
#include <hip/hip_runtime.h>
#include <math.h>

// ---------------------------------------------------------------------------
// SeasonalFNO1D: B=64, T=8192, F=6, MODES=32, WIDTH=64, LAYERS=4, FC1=128, OUT=7
// x stored PACKED: u32 = (bf16_hi << 16) | bf16_lo  (split-bf16, ~2^-16 rel).
// combine (irfft+conv+gelu) = MFMA GEMM: A=[cos|sin|x] (K=128, split -> 3 terms),
//   B=[wr';wi';conv_w] prebuilt in Bw (bf16 hi|lo, K=256 layout).
// dft stays VALU this round (LDS-broadcast twiddles).
// ---------------------------------------------------------------------------

constexpr int B = 64, T = 8192, F = 6, MODES = 32, C = 64, FC1N = 128, OUTN = 7;
constexpr int TMASK = T - 1;
constexpr int NCH = 4, TS = T / NCH;     // dft chunking (512-thread blocks)
constexpr int GCH = 8;                   // combine: chunks (64 rows) per block

typedef __attribute__((ext_vector_type(4))) float f32x4;
typedef __attribute__((ext_vector_type(8))) short s16x8;

__device__ __forceinline__ float gelu_exact(float v) {
    return 0.5f * v * (1.0f + erff(v * 0.70710678118654752f));
}
__device__ __forceinline__ unsigned short bf16_rne(float f) {
    unsigned u = __float_as_uint(f);
    unsigned r = u + 0x7FFFu + ((u >> 16) & 1u);
    return (unsigned short)(r >> 16);
}
__device__ __forceinline__ float bf16_f(unsigned short h) {
    return __uint_as_float(((unsigned)h) << 16);
}
__device__ __forceinline__ unsigned pack_split(float v) {
    unsigned short hi = bf16_rne(v);
    float lo = v - bf16_f(hi);
    return (((unsigned)hi) << 16) | (unsigned)bf16_rne(lo);
}
__device__ __forceinline__ float unpack_f32(unsigned u) {
    return __uint_as_float(u & 0xFFFF0000u) + __uint_as_float(u << 16);
}
__device__ __forceinline__ s16x8 u4_to_s8(uint4 v) {
    union { uint4 u; s16x8 s; } cv; cv.u = v; return cv.s;
}
// (h1<<16)|h0 and (l1<<16)|l0 from packed pairs
__device__ __forceinline__ s16x8 hi8(uint4 p0, uint4 p1) {
    uint4 h;
    h.x = __byte_perm(p0.x, p0.y, 0x7632); h.y = __byte_perm(p0.z, p0.w, 0x7632);
    h.z = __byte_perm(p1.x, p1.y, 0x7632); h.w = __byte_perm(p1.z, p1.w, 0x7632);
    return u4_to_s8(h);
}
__device__ __forceinline__ s16x8 lo8(uint4 p0, uint4 p1) {
    uint4 h;
    h.x = __byte_perm(p0.x, p0.y, 0x5410); h.y = __byte_perm(p0.z, p0.w, 0x5410);
    h.z = __byte_perm(p1.x, p1.y, 0x5410); h.w = __byte_perm(p1.z, p1.w, 0x5410);
    return u4_to_s8(h);
}

// tw[n] = (cos, sin)(2*pi*n/T)  -- float2 base table (dft + final)
__global__ void twid_k(float2* __restrict__ tw) {
    int n = blockIdx.x * 256 + threadIdx.x;
    double th = 6.283185307179586476925286766559 * (double)n / (double)T;
    tw[n] = make_float2((float)cos(th), (float)sin(th));
}

// twdH/twdL[t][j]: j<32: cos(2*pi*j*t/T); j>=32: sin(2*pi*(j-32)*t/T), split bf16
__global__ void twdtab_k(unsigned short* __restrict__ twdH, unsigned short* __restrict__ twdL) {
    int i = blockIdx.x * 256 + threadIdx.x;
    int t = i >> 6, j = i & 63, k = j & 31;
    int m = (k * t) & TMASK;
    double th = 6.283185307179586476925286766559 * (double)m / (double)T;
    float v = (float)((j < 32) ? cos(th) : sin(th));
    unsigned short hi = bf16_rne(v);
    twdH[i] = hi;
    twdL[i] = bf16_rne(v - bf16_f(hi));
}

// x[row, c] = sum_f in[row, f] * w[f, c] + b[c]   (packed split output)
__global__ void fc0_k(const float* __restrict__ in, const float* __restrict__ w,
                      const float* __restrict__ bias, unsigned* __restrict__ x) {
    int tid = threadIdx.x;
    size_t row = (size_t)blockIdx.x * 4 + (tid >> 6);
    int c = tid & 63;
    const float* ip = in + row * F;
    float acc = bias[c];
#pragma unroll
    for (int f = 0; f < F; f++) acc = fmaf(ip[f], w[f * C + c], acc);
    x[row * C + c] = pack_split(acc);
}

// Partial pruned DFT. grid (NCH, B), 512 thr: lane c = tid&63, wave kq = tid>>6 (8 waves),
// each wave handles k = kq*4+j, j<4, over TS t's.
__global__ void __launch_bounds__(512) dft_partial(const unsigned* __restrict__ x,
                                                   const float2* __restrict__ tw,
                                                   float2* __restrict__ part) {
    __shared__ float2 ltw[T];  // 64 KiB
    int b = blockIdx.y, ch = blockIdx.x, tid = threadIdx.x;
    for (int i = tid; i < T; i += 512) ltw[i] = tw[i];
    __syncthreads();
    int c = tid & 63, kq = tid >> 6;
    float accr[4], acci[4];
    int n[4];
    int t0 = ch * TS;
#pragma unroll
    for (int j = 0; j < 4; j++) {
        accr[j] = 0.f; acci[j] = 0.f;
        n[j] = ((kq * 4 + j) * t0) & TMASK;
    }
    const unsigned* xp = x + ((size_t)b * T + t0) * C + c;
    for (int t = 0; t < TS; t++) {
        float xv = unpack_f32(xp[(size_t)t * C]);
#pragma unroll
        for (int j = 0; j < 4; j++) {
            float2 w = ltw[n[j]];
            accr[j] = fmaf(xv, w.x, accr[j]);
            acci[j] = fmaf(-xv, w.y, acci[j]);
            n[j] = (n[j] + kq * 4 + j) & TMASK;
        }
    }
#pragma unroll
    for (int j = 0; j < 4; j++) {
        int k = kq * 4 + j;
        part[(((size_t)b * NCH + ch) * MODES + k) * C + c] = make_float2(accr[j], acci[j]);
    }
}

// Reduce partials + complex mode mix: Y[b,k,o] = sum_c X[b,k,c]*(wr+i wi)[k,c,o]
__global__ void mode_mix(const float2* __restrict__ part, const float* __restrict__ wr,
                         const float* __restrict__ wi, float2* __restrict__ Y) {
    int b = blockIdx.y, k = blockIdx.x, o = threadIdx.x;
    __shared__ float xr[C], xi[C];
    float sr = 0.f, si = 0.f;
    for (int ch = 0; ch < NCH; ch++) {
        float2 p = part[(((size_t)b * NCH + ch) * MODES + k) * C + o];
        sr += p.x; si += p.y;
    }
    xr[o] = sr; xi[o] = si;
    __syncthreads();
    float ar = 0.f, ai = 0.f;
    for (int c = 0; c < C; c++) {
        float wrr = wr[((size_t)k * C + c) * C + o];
        float wii = wi[((size_t)k * C + c) * C + o];
        float Xr = xr[c], Xi = xi[c];
        ar = fmaf(Xr, wrr, ar); ar = fmaf(-Xi, wii, ar);
        ai = fmaf(Xr, wii, ai); ai = fmaf(Xi, wrr, ai);
    }
    Y[((size_t)b * MODES + k) * C + o] = make_float2(ar, ai);
}

// Build per-batch GEMM weights Bw[b][o][kc] bf16 (kc<128: hi, kc>=128: lo).
// Rows (k-space): 0..31 = wr'[k]= s_k/T*Yr; 32..63 = -2/T*Yi; 64..127 = conv_w.
__global__ void bweights_k(const float2* __restrict__ Y, const float* __restrict__ cw,
                           unsigned short* __restrict__ Bw) {
    int b = blockIdx.x, tid = threadIdx.x;
    const float invT = 1.0f / (float)T;
    for (int i = tid; i < C * 256; i += 256) {
        int o = i >> 8, kc = i & 255;
        int src = kc & 127, half = kc >> 7;
        float w;
        if (src < 32) {
            float s = (src == 0) ? invT : 2.0f * invT;
            w = s * Y[((size_t)b * MODES + src) * C + o].x;
        } else if (src < 64) {
            w = (-2.0f * invT) * Y[((size_t)b * MODES + (src - 32)) * C + o].y;
        } else {
            w = cw[(size_t)(src - 64) * C + o];
        }
        unsigned short hi = bf16_rne(w);
        Bw[((size_t)b * C + o) * 256 + kc] = half ? bf16_rne(w - bf16_f(hi)) : hi;
    }
}

// MFMA irfft+conv+gelu, in-place on packed x.
// grid (T/(64*GCH), B), 256 thr = 4 waves; wave wv owns output cols [wv*16, wv*16+16).
// Per chunk (64 rows): 4 m-tiles of 16 rows; split-bf16 3-term GEMM, K=128.
__global__ void __launch_bounds__(256) combine_mfma(unsigned* __restrict__ xp,
                                                    const unsigned short* __restrict__ twdH,
                                                    const unsigned short* __restrict__ twdL,
                                                    const unsigned short* __restrict__ Bw,
                                                    const float* __restrict__ cb) {
    int b = blockIdx.y;
    int tid = threadIdx.x;
    int wv = tid >> 6, lane = tid & 63;
    int lm = lane & 15, quad = lane >> 4;
    int ncol = wv * 16 + lm;
    size_t bT = (size_t)b * T;

    // B fragments (reg-resident for whole block): Bw[b][ncol][32*i + quad*8 ..+8]
    const unsigned short* bwp = Bw + ((size_t)b * C + ncol) * 256 + quad * 8;
    s16x8 bf0 = *(const s16x8*)(bwp + 0);
    s16x8 bf1 = *(const s16x8*)(bwp + 32);
    s16x8 bf2 = *(const s16x8*)(bwp + 64);
    s16x8 bf3 = *(const s16x8*)(bwp + 96);
    s16x8 bf4 = *(const s16x8*)(bwp + 128);
    s16x8 bf5 = *(const s16x8*)(bwp + 160);
    s16x8 bf6 = *(const s16x8*)(bwp + 192);
    s16x8 bf7 = *(const s16x8*)(bwp + 224);
    float cbv = cb[ncol];

    int g0 = blockIdx.x * GCH;
    for (int g = 0; g < GCH; g++) {
        int t0 = (g0 + g) * 64;
        f32x4 acc[4];
#pragma unroll
        for (int mt = 0; mt < 4; mt++) acc[mt] = (f32x4){0.f, 0.f, 0.f, 0.f};

#pragma unroll
        for (int mt = 0; mt < 4; mt++) {
            int t = t0 + mt * 16 + lm;
            const unsigned short* thp = twdH + (size_t)t * C + quad * 8;
            const unsigned short* tlp = twdL + (size_t)t * C + quad * 8;
            const unsigned* xr = xp + (bT + t) * C + quad * 8;
            s16x8 a;
            // tw-hi (cos, sin) with B_hi and B_lo
            a = *(const s16x8*)thp;
            acc[mt] = __builtin_amdgcn_mfma_f32_16x16x32_bf16(a, bf0, acc[mt], 0, 0, 0);
            acc[mt] = __builtin_amdgcn_mfma_f32_16x16x32_bf16(a, bf4, acc[mt], 0, 0, 0);
            a = *(const s16x8*)(thp + 32);
            acc[mt] = __builtin_amdgcn_mfma_f32_16x16x32_bf16(a, bf1, acc[mt], 0, 0, 0);
            acc[mt] = __builtin_amdgcn_mfma_f32_16x16x32_bf16(a, bf5, acc[mt], 0, 0, 0);
            // x-hi with B_hi and B_lo
            uint4 p0 = *(const uint4*)xr;
            uint4 p1 = *(const uint4*)(xr + 4);
            a = hi8(p0, p1);
            acc[mt] = __builtin_amdgcn_mfma_f32_16x16x32_bf16(a, bf2, acc[mt], 0, 0, 0);
            acc[mt] = __builtin_amdgcn_mfma_f32_16x16x32_bf16(a, bf6, acc[mt], 0, 0, 0);
            uint4 p2 = *(const uint4*)(xr + 32);
            uint4 p3 = *(const uint4*)(xr + 36);
            a = hi8(p2, p3);
            acc[mt] = __builtin_amdgcn_mfma_f32_16x16x32_bf16(a, bf3, acc[mt], 0, 0, 0);
            acc[mt] = __builtin_amdgcn_mfma_f32_16x16x32_bf16(a, bf7, acc[mt], 0, 0, 0);
            // lo terms with B_hi
            a = *(const s16x8*)tlp;
            acc[mt] = __builtin_amdgcn_mfma_f32_16x16x32_bf16(a, bf0, acc[mt], 0, 0, 0);
            a = *(const s16x8*)(tlp + 32);
            acc[mt] = __builtin_amdgcn_mfma_f32_16x16x32_bf16(a, bf1, acc[mt], 0, 0, 0);
            a = lo8(p0, p1);
            acc[mt] = __builtin_amdgcn_mfma_f32_16x16x32_bf16(a, bf2, acc[mt], 0, 0, 0);
            a = lo8(p2, p3);
            acc[mt] = __builtin_amdgcn_mfma_f32_16x16x32_bf16(a, bf3, acc[mt], 0, 0, 0);
        }
        // all waves' reads of this chunk's x must complete before in-place writes
        __syncthreads();
#pragma unroll
        for (int mt = 0; mt < 4; mt++) {
#pragma unroll
            for (int r = 0; r < 4; r++) {
                int t = t0 + mt * 16 + quad * 4 + r;
                float v = acc[mt][r] + cbv;
                xp[(bT + t) * C + ncol] = pack_split(gelu_exact(v));
            }
        }
    }
}

// Layer 3 at t=T-1 only, then fc1+gelu, fc2. grid B, 128 threads.
__global__ void final_k(const unsigned* __restrict__ x3, const float2* __restrict__ Y3,
                        const float2* __restrict__ tw, const float* __restrict__ cw,
                        const float* __restrict__ cb, const float* __restrict__ w1,
                        const float* __restrict__ b1, const float* __restrict__ w2,
                        const float* __restrict__ b2, float* __restrict__ out) {
    int b = blockIdx.x, tid = threadIdx.x;
    __shared__ float xrow[C];
    __shared__ float xl[C];
    __shared__ float h[FC1N];
    if (tid < C) xrow[tid] = unpack_f32(x3[((size_t)b * T + (T - 1)) * C + tid]);
    __syncthreads();
    if (tid < C) {
        int o = tid;
        const float2* Yb = Y3 + (size_t)b * (MODES * C);
        float a2 = 0.f;
        for (int k = 1; k < MODES; k++) {
            float2 w = tw[(k * (T - 1)) & TMASK];
            float2 y = Yb[k * C + o];
            a2 = fmaf(y.x, w.x, a2);
            a2 = fmaf(-y.y, w.y, a2);
        }
        float xf = (Yb[o].x + 2.f * a2) * (1.0f / (float)T);
        float cv = cb[o];
        for (int c = 0; c < C; c++) cv = fmaf(xrow[c], cw[c * C + o], cv);
        xl[o] = gelu_exact(xf + cv);
    }
    __syncthreads();
    {
        int j = tid;
        float acc = b1[j];
        for (int c = 0; c < C; c++) acc = fmaf(xl[c], w1[c * FC1N + j], acc);
        h[j] = gelu_exact(acc);
    }
    __syncthreads();
    if (tid < OUTN) {
        float acc = b2[tid];
        for (int j = 0; j < FC1N; j++) acc = fmaf(h[j], w2[j * OUTN + tid], acc);
        out[b * OUTN + tid] = acc;
    }
}

extern "C" void kernel_launch(void* const* d_in, const int* in_sizes, int n_in,
                              void* d_out, int out_size, void* d_ws, size_t ws_size,
                              hipStream_t stream) {
    const float* inp   = (const float*)d_in[0];
    const float* fc0_w = (const float*)d_in[1];
    const float* fc0_b = (const float*)d_in[2];
    const float* fwr   = (const float*)d_in[3];
    const float* fwi   = (const float*)d_in[4];
    const float* cw    = (const float*)d_in[5];
    const float* cb    = (const float*)d_in[6];
    const float* w1    = (const float*)d_in[7];
    const float* b1    = (const float*)d_in[8];
    const float* w2    = (const float*)d_in[9];
    const float* b2    = (const float*)d_in[10];
    float* out = (float*)d_out;

    // Workspace layout (total = 143,720,448 B, same as validated round-1 footprint)
    char* ws = (char*)d_ws;
    unsigned* x = (unsigned*)ws;                                  // 134,217,728
    size_t off = (size_t)B * T * C * sizeof(unsigned);
    float2* part = (float2*)(ws + off);                           //   4,194,304
    off += (size_t)B * NCH * MODES * C * sizeof(float2);
    float2* Y = (float2*)(ws + off);                              //   1,048,576
    off += (size_t)B * MODES * C * sizeof(float2);
    unsigned short* twdH = (unsigned short*)(ws + off);           //   1,048,576
    off += (size_t)T * C * sizeof(unsigned short);
    unsigned short* twdL = (unsigned short*)(ws + off);           //   1,048,576
    off += (size_t)T * C * sizeof(unsigned short);
    unsigned short* Bw = (unsigned short*)(ws + off);             //   2,097,152
    off += (size_t)B * C * 256 * sizeof(unsigned short);
    float2* tw = (float2*)(ws + off);                             //      65,536

    twid_k<<<T / 256, 256, 0, stream>>>(tw);
    twdtab_k<<<(T * C) / 256, 256, 0, stream>>>(twdH, twdL);
    fc0_k<<<B * T / 4, 256, 0, stream>>>(inp, fc0_w, fc0_b, x);

    for (int l = 0; l < 4; l++) {
        dft_partial<<<dim3(NCH, B), 512, 0, stream>>>(x, tw, part);
        mode_mix<<<dim3(MODES, B), 64, 0, stream>>>(part, fwr + (size_t)l * MODES * C * C,
                                                    fwi + (size_t)l * MODES * C * C, Y);
        if (l < 3) {
            bweights_k<<<B, 256, 0, stream>>>(Y, cw + (size_t)l * C * C, Bw);
            combine_mfma<<<dim3(T / (64 * GCH), B), 256, 0, stream>>>(x, twdH, twdL, Bw,
                                                                      cb + (size_t)l * C);
        }
    }
    final_k<<<B, FC1N, 0, stream>>>(x, Y, tw, cw + (size_t)3 * C * C, cb + (size_t)3 * C,
                                    w1, b1, w2, b2, out);
}

// Round 3
// 801.965 us; speedup vs baseline: 3.0832x; 1.6645x over previous
//
#include <hip/hip_runtime.h>
#include <math.h>

// ---------------------------------------------------------------------------
// SeasonalFNO1D: B=64, T=8192, F=6, MODES=32, WIDTH=64, LAYERS=4, FC1=128, OUT=7
// x stored PACKED: u32 = (bf16_hi << 16) | bf16_lo  (split-bf16, ~2^-16 rel).
// combine (irfft+conv+gelu) = MFMA GEMM: A=[cos|sin|x] (K=128, split -> 3 terms),
//   B=[wr';wi';conv_w] prebuilt in Bw (bf16 hi|lo, K=256 layout).
// dft = MFMA GEMM: D[j,c] = sum_t twdT[j,t]*x[t,c], j<32 cos rows, j>=32 sin rows,
//   split-bf16 3 terms; B-frags read direct from global (L1 absorbs 4x dup).
// part (split-u32) aliases Bw in ws: lifetimes disjoint within a layer.
// ---------------------------------------------------------------------------

constexpr int B = 64, T = 8192, F = 6, MODES = 32, C = 64, FC1N = 128, OUTN = 7;
constexpr int TMASK = T - 1;
constexpr int NCH = 4, TS = T / NCH;     // dft chunking
constexpr int KSTEPS = TS / 32;          // 64 k-steps of K=32
constexpr int GCH = 8;                   // combine: chunks (64 rows) per block

typedef __attribute__((ext_vector_type(4))) float f32x4;
typedef __attribute__((ext_vector_type(8))) short s16x8;

__device__ __forceinline__ float gelu_exact(float v) {
    return 0.5f * v * (1.0f + erff(v * 0.70710678118654752f));
}
__device__ __forceinline__ unsigned short bf16_rne(float f) {
    unsigned u = __float_as_uint(f);
    unsigned r = u + 0x7FFFu + ((u >> 16) & 1u);
    return (unsigned short)(r >> 16);
}
__device__ __forceinline__ float bf16_f(unsigned short h) {
    return __uint_as_float(((unsigned)h) << 16);
}
__device__ __forceinline__ unsigned pack_split(float v) {
    unsigned short hi = bf16_rne(v);
    float lo = v - bf16_f(hi);
    return (((unsigned)hi) << 16) | (unsigned)bf16_rne(lo);
}
__device__ __forceinline__ float unpack_f32(unsigned u) {
    return __uint_as_float(u & 0xFFFF0000u) + __uint_as_float(u << 16);
}
__device__ __forceinline__ s16x8 u4_to_s8(uint4 v) {
    union { uint4 u; s16x8 s; } cv; cv.u = v; return cv.s;
}
__device__ __forceinline__ s16x8 hi8(uint4 p0, uint4 p1) {
    uint4 h;
    h.x = __byte_perm(p0.x, p0.y, 0x7632); h.y = __byte_perm(p0.z, p0.w, 0x7632);
    h.z = __byte_perm(p1.x, p1.y, 0x7632); h.w = __byte_perm(p1.z, p1.w, 0x7632);
    return u4_to_s8(h);
}
__device__ __forceinline__ s16x8 lo8(uint4 p0, uint4 p1) {
    uint4 h;
    h.x = __byte_perm(p0.x, p0.y, 0x5410); h.y = __byte_perm(p0.z, p0.w, 0x5410);
    h.z = __byte_perm(p1.x, p1.y, 0x5410); h.w = __byte_perm(p1.z, p1.w, 0x5410);
    return u4_to_s8(h);
}

// twdH/twdL[t][j]: j<32: cos(2*pi*j*t/T); j>=32: sin(2*pi*(j-32)*t/T), split bf16
// (A-operand layout for combine: lane m=t, contiguous in j)
__global__ void twdtab_k(unsigned short* __restrict__ twdH, unsigned short* __restrict__ twdL) {
    int i = blockIdx.x * 256 + threadIdx.x;
    int t = i >> 6, j = i & 63, k = j & 31;
    int m = (k * t) & TMASK;
    double th = 6.283185307179586476925286766559 * (double)m / (double)T;
    float v = (float)((j < 32) ? cos(th) : sin(th));
    unsigned short hi = bf16_rne(v);
    twdH[i] = hi;
    twdL[i] = bf16_rne(v - bf16_f(hi));
}

// twdTP[j][t] packed split-u32 (A-operand layout for dft: lane m=j, contiguous in t)
__global__ void twdtabT_k(unsigned* __restrict__ twdTP) {
    int i = blockIdx.x * 256 + threadIdx.x;   // 64*8192
    int j = i >> 13, t = i & TMASK, k = j & 31;
    int m = (k * t) & TMASK;
    double th = 6.283185307179586476925286766559 * (double)m / (double)T;
    float v = (float)((j < 32) ? cos(th) : sin(th));
    twdTP[i] = pack_split(v);
}

// x[row, c] = sum_f in[row, f] * w[f, c] + b[c]   (packed split output)
__global__ void fc0_k(const float* __restrict__ in, const float* __restrict__ w,
                      const float* __restrict__ bias, unsigned* __restrict__ x) {
    int tid = threadIdx.x;
    size_t row = (size_t)blockIdx.x * 4 + (tid >> 6);
    int c = tid & 63;
    const float* ip = in + row * F;
    float acc = bias[c];
#pragma unroll
    for (int f = 0; f < F; f++) acc = fmaf(ip[f], w[f * C + c], acc);
    x[row * C + c] = pack_split(acc);
}

// MFMA pruned DFT. grid (NCH, B), 512 thr = 8 waves: wave w -> (mt = w&3, nh = w>>2).
// D[j = mt*16+quad*4+r][c = nh*32+nt*16+l15]; j<32: +sum x cos; j>=32: stored as -sum x sin.
// part[((b*NCH+ch)*64 + j)*64 + c] packed split-u32.
__global__ void __launch_bounds__(512) dft_mfma(const unsigned* __restrict__ x,
                                                const unsigned* __restrict__ twdTP,
                                                unsigned* __restrict__ part) {
    int b = blockIdx.y, ch = blockIdx.x, tid = threadIdx.x;
    int w = tid >> 6, lane = tid & 63;
    int l15 = lane & 15, quad = lane >> 4;
    int mt = w & 3, nh = w >> 2;
    size_t bT = (size_t)b * T;
    int t0 = ch * TS;

    const unsigned* ap = twdTP + (size_t)(mt * 16 + l15) * T + t0 + quad * 8;
    const unsigned* bp0 = x + (bT + t0 + quad * 8) * C + nh * 32 + l15;
    const unsigned* bp1 = bp0 + 16;

    f32x4 acc0 = {0.f, 0.f, 0.f, 0.f};
    f32x4 acc1 = {0.f, 0.f, 0.f, 0.f};

    for (int ks = 0; ks < KSTEPS; ks++) {
        uint4 a0 = *(const uint4*)(ap);
        uint4 a1 = *(const uint4*)(ap + 4);
        ap += 32;
        s16x8 ah = hi8(a0, a1), al = lo8(a0, a1);

        uint4 p0, p1;
        p0.x = bp0[0 * C]; p0.y = bp0[1 * C]; p0.z = bp0[2 * C]; p0.w = bp0[3 * C];
        p1.x = bp0[4 * C]; p1.y = bp0[5 * C]; p1.z = bp0[6 * C]; p1.w = bp0[7 * C];
        s16x8 bh = hi8(p0, p1), bl = lo8(p0, p1);
        acc0 = __builtin_amdgcn_mfma_f32_16x16x32_bf16(ah, bh, acc0, 0, 0, 0);
        acc0 = __builtin_amdgcn_mfma_f32_16x16x32_bf16(ah, bl, acc0, 0, 0, 0);
        acc0 = __builtin_amdgcn_mfma_f32_16x16x32_bf16(al, bh, acc0, 0, 0, 0);

        p0.x = bp1[0 * C]; p0.y = bp1[1 * C]; p0.z = bp1[2 * C]; p0.w = bp1[3 * C];
        p1.x = bp1[4 * C]; p1.y = bp1[5 * C]; p1.z = bp1[6 * C]; p1.w = bp1[7 * C];
        bh = hi8(p0, p1); bl = lo8(p0, p1);
        acc1 = __builtin_amdgcn_mfma_f32_16x16x32_bf16(ah, bh, acc1, 0, 0, 0);
        acc1 = __builtin_amdgcn_mfma_f32_16x16x32_bf16(ah, bl, acc1, 0, 0, 0);
        acc1 = __builtin_amdgcn_mfma_f32_16x16x32_bf16(al, bh, acc1, 0, 0, 0);

        bp0 += 32 * C;
        bp1 += 32 * C;
    }

    float sgn = (mt >= 2) ? -1.f : 1.f;
    size_t base = ((size_t)b * NCH + ch) * 64;
#pragma unroll
    for (int r = 0; r < 4; r++) {
        int j = mt * 16 + quad * 4 + r;
        int c0 = nh * 32 + l15;
        part[(base + j) * 64 + c0]      = pack_split(sgn * acc0[r]);
        part[(base + j) * 64 + c0 + 16] = pack_split(sgn * acc1[r]);
    }
}

// Reduce partials + complex mode mix: Y[b,k,o] = sum_c X[b,k,c]*(wr+i wi)[k,c,o]
__global__ void mode_mix(const unsigned* __restrict__ part, const float* __restrict__ wr,
                         const float* __restrict__ wi, float2* __restrict__ Y) {
    int b = blockIdx.y, k = blockIdx.x, o = threadIdx.x;
    __shared__ float xr[C], xi[C];
    float sr = 0.f, si = 0.f;
    for (int ch = 0; ch < NCH; ch++) {
        size_t base = ((size_t)b * NCH + ch) * 64;
        sr += unpack_f32(part[(base + k) * 64 + o]);
        si += unpack_f32(part[(base + 32 + k) * 64 + o]);
    }
    xr[o] = sr; xi[o] = si;
    __syncthreads();
    float ar = 0.f, ai = 0.f;
    for (int c = 0; c < C; c++) {
        float wrr = wr[((size_t)k * C + c) * C + o];
        float wii = wi[((size_t)k * C + c) * C + o];
        float Xr = xr[c], Xi = xi[c];
        ar = fmaf(Xr, wrr, ar); ar = fmaf(-Xi, wii, ar);
        ai = fmaf(Xr, wii, ai); ai = fmaf(Xi, wrr, ai);
    }
    Y[((size_t)b * MODES + k) * C + o] = make_float2(ar, ai);
}

// Build per-batch GEMM weights Bw[b][o][kc] bf16 (kc<128: hi, kc>=128: lo).
__global__ void bweights_k(const float2* __restrict__ Y, const float* __restrict__ cw,
                           unsigned short* __restrict__ Bw) {
    int b = blockIdx.x, tid = threadIdx.x;
    const float invT = 1.0f / (float)T;
    for (int i = tid; i < C * 256; i += 256) {
        int o = i >> 8, kc = i & 255;
        int src = kc & 127, half = kc >> 7;
        float w;
        if (src < 32) {
            float s = (src == 0) ? invT : 2.0f * invT;
            w = s * Y[((size_t)b * MODES + src) * C + o].x;
        } else if (src < 64) {
            w = (-2.0f * invT) * Y[((size_t)b * MODES + (src - 32)) * C + o].y;
        } else {
            w = cw[(size_t)(src - 64) * C + o];
        }
        unsigned short hi = bf16_rne(w);
        Bw[((size_t)b * C + o) * 256 + kc] = half ? bf16_rne(w - bf16_f(hi)) : hi;
    }
}

// MFMA irfft+conv+gelu, in-place on packed x.
__global__ void __launch_bounds__(256) combine_mfma(unsigned* __restrict__ xp,
                                                    const unsigned short* __restrict__ twdH,
                                                    const unsigned short* __restrict__ twdL,
                                                    const unsigned short* __restrict__ Bw,
                                                    const float* __restrict__ cb) {
    int b = blockIdx.y;
    int tid = threadIdx.x;
    int wv = tid >> 6, lane = tid & 63;
    int lm = lane & 15, quad = lane >> 4;
    int ncol = wv * 16 + lm;
    size_t bT = (size_t)b * T;

    const unsigned short* bwp = Bw + ((size_t)b * C + ncol) * 256 + quad * 8;
    s16x8 bf0 = *(const s16x8*)(bwp + 0);
    s16x8 bf1 = *(const s16x8*)(bwp + 32);
    s16x8 bf2 = *(const s16x8*)(bwp + 64);
    s16x8 bf3 = *(const s16x8*)(bwp + 96);
    s16x8 bf4 = *(const s16x8*)(bwp + 128);
    s16x8 bf5 = *(const s16x8*)(bwp + 160);
    s16x8 bf6 = *(const s16x8*)(bwp + 192);
    s16x8 bf7 = *(const s16x8*)(bwp + 224);
    float cbv = cb[ncol];

    int g0 = blockIdx.x * GCH;
    for (int g = 0; g < GCH; g++) {
        int t0 = (g0 + g) * 64;
        f32x4 acc[4];
#pragma unroll
        for (int mt = 0; mt < 4; mt++) acc[mt] = (f32x4){0.f, 0.f, 0.f, 0.f};

#pragma unroll
        for (int mt = 0; mt < 4; mt++) {
            int t = t0 + mt * 16 + lm;
            const unsigned short* thp = twdH + (size_t)t * C + quad * 8;
            const unsigned short* tlp = twdL + (size_t)t * C + quad * 8;
            const unsigned* xr = xp + (bT + t) * C + quad * 8;
            s16x8 a;
            a = *(const s16x8*)thp;
            acc[mt] = __builtin_amdgcn_mfma_f32_16x16x32_bf16(a, bf0, acc[mt], 0, 0, 0);
            acc[mt] = __builtin_amdgcn_mfma_f32_16x16x32_bf16(a, bf4, acc[mt], 0, 0, 0);
            a = *(const s16x8*)(thp + 32);
            acc[mt] = __builtin_amdgcn_mfma_f32_16x16x32_bf16(a, bf1, acc[mt], 0, 0, 0);
            acc[mt] = __builtin_amdgcn_mfma_f32_16x16x32_bf16(a, bf5, acc[mt], 0, 0, 0);
            uint4 p0 = *(const uint4*)xr;
            uint4 p1 = *(const uint4*)(xr + 4);
            a = hi8(p0, p1);
            acc[mt] = __builtin_amdgcn_mfma_f32_16x16x32_bf16(a, bf2, acc[mt], 0, 0, 0);
            acc[mt] = __builtin_amdgcn_mfma_f32_16x16x32_bf16(a, bf6, acc[mt], 0, 0, 0);
            uint4 p2 = *(const uint4*)(xr + 32);
            uint4 p3 = *(const uint4*)(xr + 36);
            a = hi8(p2, p3);
            acc[mt] = __builtin_amdgcn_mfma_f32_16x16x32_bf16(a, bf3, acc[mt], 0, 0, 0);
            acc[mt] = __builtin_amdgcn_mfma_f32_16x16x32_bf16(a, bf7, acc[mt], 0, 0, 0);
            a = *(const s16x8*)tlp;
            acc[mt] = __builtin_amdgcn_mfma_f32_16x16x32_bf16(a, bf0, acc[mt], 0, 0, 0);
            a = *(const s16x8*)(tlp + 32);
            acc[mt] = __builtin_amdgcn_mfma_f32_16x16x32_bf16(a, bf1, acc[mt], 0, 0, 0);
            a = lo8(p0, p1);
            acc[mt] = __builtin_amdgcn_mfma_f32_16x16x32_bf16(a, bf2, acc[mt], 0, 0, 0);
            a = lo8(p2, p3);
            acc[mt] = __builtin_amdgcn_mfma_f32_16x16x32_bf16(a, bf3, acc[mt], 0, 0, 0);
        }
        __syncthreads();
#pragma unroll
        for (int mt = 0; mt < 4; mt++) {
#pragma unroll
            for (int r = 0; r < 4; r++) {
                int t = t0 + mt * 16 + quad * 4 + r;
                float v = acc[mt][r] + cbv;
                xp[(bT + t) * C + ncol] = pack_split(gelu_exact(v));
            }
        }
    }
}

// Layer 3 at t=T-1 only, then fc1+gelu, fc2. grid B, 128 threads.
__global__ void final_k(const unsigned* __restrict__ x3, const float2* __restrict__ Y3,
                        const float* __restrict__ cw, const float* __restrict__ cb,
                        const float* __restrict__ w1, const float* __restrict__ b1,
                        const float* __restrict__ w2, const float* __restrict__ b2,
                        float* __restrict__ out) {
    int b = blockIdx.x, tid = threadIdx.x;
    __shared__ float xrow[C];
    __shared__ float xl[C];
    __shared__ float h[FC1N];
    if (tid < C) xrow[tid] = unpack_f32(x3[((size_t)b * T + (T - 1)) * C + tid]);
    __syncthreads();
    if (tid < C) {
        int o = tid;
        const float2* Yb = Y3 + (size_t)b * (MODES * C);
        float a2 = 0.f;
        for (int k = 1; k < MODES; k++) {
            // twiddle at t=T-1: m=(k*(T-1))&TMASK = T-k -> cos=cos(2pi k/T), sin=-sin(2pi k/T)
            float thk = 7.6699039394282067e-4f * (float)k;
            float cwv = cosf(thk), swv = -sinf(thk);
            float2 y = Yb[k * C + o];
            a2 = fmaf(y.x, cwv, a2);
            a2 = fmaf(-y.y, swv, a2);
        }
        float xf = (Yb[o].x + 2.f * a2) * (1.0f / (float)T);
        float cv = cb[o];
        for (int c = 0; c < C; c++) cv = fmaf(xrow[c], cw[c * C + o], cv);
        xl[o] = gelu_exact(xf + cv);
    }
    __syncthreads();
    {
        int j = tid;
        float acc = b1[j];
        for (int c = 0; c < C; c++) acc = fmaf(xl[c], w1[c * FC1N + j], acc);
        h[j] = gelu_exact(acc);
    }
    __syncthreads();
    if (tid < OUTN) {
        float acc = b2[tid];
        for (int j = 0; j < FC1N; j++) acc = fmaf(h[j], w2[j * OUTN + tid], acc);
        out[b * OUTN + tid] = acc;
    }
}

extern "C" void kernel_launch(void* const* d_in, const int* in_sizes, int n_in,
                              void* d_out, int out_size, void* d_ws, size_t ws_size,
                              hipStream_t stream) {
    const float* inp   = (const float*)d_in[0];
    const float* fc0_w = (const float*)d_in[1];
    const float* fc0_b = (const float*)d_in[2];
    const float* fwr   = (const float*)d_in[3];
    const float* fwi   = (const float*)d_in[4];
    const float* cw    = (const float*)d_in[5];
    const float* cb    = (const float*)d_in[6];
    const float* w1    = (const float*)d_in[7];
    const float* b1    = (const float*)d_in[8];
    const float* w2    = (const float*)d_in[9];
    const float* b2    = (const float*)d_in[10];
    float* out = (float*)d_out;

    // Workspace layout (total 143,654,912 B <= proven 143,720,448)
    char* ws = (char*)d_ws;
    unsigned* x = (unsigned*)ws;                                  // 134,217,728
    size_t off = (size_t)B * T * C * sizeof(unsigned);
    unsigned* part = (unsigned*)(ws + off);                       //   4,194,304
    unsigned short* Bw = (unsigned short*)(ws + off);             //   (aliases part: disjoint lifetimes)
    off += (size_t)B * NCH * 64 * 64 * sizeof(unsigned);
    float2* Y = (float2*)(ws + off);                              //   1,048,576
    off += (size_t)B * MODES * C * sizeof(float2);
    unsigned short* twdH = (unsigned short*)(ws + off);           //   1,048,576
    off += (size_t)T * C * sizeof(unsigned short);
    unsigned short* twdL = (unsigned short*)(ws + off);           //   1,048,576
    off += (size_t)T * C * sizeof(unsigned short);
    unsigned* twdTP = (unsigned*)(ws + off);                      //   2,097,152
    off += (size_t)64 * T * sizeof(unsigned);

    twdtab_k<<<(T * C) / 256, 256, 0, stream>>>(twdH, twdL);
    twdtabT_k<<<(64 * T) / 256, 256, 0, stream>>>(twdTP);
    fc0_k<<<B * T / 4, 256, 0, stream>>>(inp, fc0_w, fc0_b, x);

    for (int l = 0; l < 4; l++) {
        dft_mfma<<<dim3(NCH, B), 512, 0, stream>>>(x, twdTP, part);
        mode_mix<<<dim3(MODES, B), 64, 0, stream>>>(part, fwr + (size_t)l * MODES * C * C,
                                                    fwi + (size_t)l * MODES * C * C, Y);
        if (l < 3) {
            bweights_k<<<B, 256, 0, stream>>>(Y, cw + (size_t)l * C * C, Bw);
            combine_mfma<<<dim3(T / (64 * GCH), B), 256, 0, stream>>>(x, twdH, twdL, Bw,
                                                                      cb + (size_t)l * C);
        }
    }
    final_k<<<B, FC1N, 0, stream>>>(x, Y, cw + (size_t)3 * C * C, cb + (size_t)3 * C,
                                    w1, b1, w2, b2, out);
}